// Round 6
// baseline (84.835 us; speedup 1.0000x reference)
//
#include <hip/hip_runtime.h>

#define NN 8192
#define FD 128
#define BK 64
#define LDSR 72   // ushorts per LDS A row (144 B, 16B-aligned rows, conflict-light)

typedef float f32x4 __attribute__((ext_vector_type(4)));
typedef short short8 __attribute__((ext_vector_type(8)));
typedef unsigned short ushort4v __attribute__((ext_vector_type(4)));
typedef unsigned short ushort8v __attribute__((ext_vector_type(8)));

__device__ __forceinline__ unsigned short f2bf(float f) {
  unsigned int u = __builtin_bit_cast(unsigned int, f);
  u += 0x7fffu + ((u >> 16) & 1u);   // round-to-nearest-even
  return (unsigned short)(u >> 16);
}
__device__ __forceinline__ float bf2f(unsigned short h) {
  unsigned int u = ((unsigned int)h) << 16;
  return __builtin_bit_cast(float, u);
}

// -------- Kernel 1: xk = x@kern (bf16), emitted as MFMA B-fragments + row-major
// bfrag[((kt*8 + cb)*64 + lane)*8 + j] = xk[kt*32 + (lane>>4)*8 + j][cb*16 + (lane&15)]
__global__ __launch_bounds__(256) void xk_kernel(
    const float* __restrict__ x, const float* __restrict__ kern,
    unsigned short* __restrict__ bfrag, unsigned short* __restrict__ xk_rm) {
  __shared__ __align__(16) unsigned short kl[FD * FD];
  __shared__ __align__(16) float xl[16 * FD];
  const int t = threadIdx.x;
  const int row0 = blockIdx.x * 16;

  #pragma unroll
  for (int j = 0; j < 16; ++j) {
    int idx = (j * 256 + t) * 4;
    f32x4 kv = *(const f32x4*)&kern[idx];
    ushort4v kw;
    #pragma unroll
    for (int q = 0; q < 4; ++q) kw[q] = f2bf(kv[q]);
    *(ushort4v*)&kl[idx] = kw;
  }
  #pragma unroll
  for (int j = 0; j < 2; ++j) {
    int idx = (j * 256 + t) * 4;
    *(f32x4*)&xl[idx] = *(const f32x4*)&x[(size_t)row0 * FD + idx];
  }
  __syncthreads();

  const int r0 = (t >> 5) * 2;
  const int c0 = (t & 31) * 4;
  float acc[2][4] = {};
  #pragma unroll 4
  for (int k = 0; k < FD; ++k) {
    ushort4v kq = *(const ushort4v*)&kl[k * FD + c0];
    float kv[4];
    #pragma unroll
    for (int q = 0; q < 4; ++q) kv[q] = bf2f(kq[q]);
    float x0 = xl[r0 * FD + k];
    float x1 = xl[(r0 + 1) * FD + k];
    #pragma unroll
    for (int q = 0; q < 4; ++q) {
      acc[0][q] += x0 * kv[q];
      acc[1][q] += x1 * kv[q];
    }
  }
  #pragma unroll
  for (int i = 0; i < 2; ++i) {
    const int r = row0 + r0 + i;
    const int kt = r >> 5;
    const int lhi = ((r >> 3) & 3) * 16;
    const int j = r & 7;
    ushort4v ow;
    #pragma unroll
    for (int q = 0; q < 4; ++q) {
      const int c = c0 + q;
      unsigned short bv = f2bf(acc[i][q]);
      ow[q] = bv;
      bfrag[(((size_t)kt * 8 + (c >> 4)) * 64 + (lhi + (c & 15))) * 8 + j] = bv;
    }
    *(ushort4v*)&xk_rm[(size_t)r * FD + c0] = ow;
  }
}

// -------- Kernel 2: barrier-free split-K MFMA, B-before-A issue order -------
// Wave owns 32 rows x 128 cols x (NN/S) K-slice. Wave-private dbuf LDS A-tile.
#define PREFETCH(Lr, stp)                                                     \
  do {                                                                        \
    _Pragma("unroll") for (int i = 0; i < 8; ++i)                             \
        Lr[i] = *(const f32x4*)(ap + (size_t)i * 4 * NN + (stp) * BK);        \
  } while (0)

#define STAGE(Lr, bufofs)                                                     \
  do {                                                                        \
    _Pragma("unroll") for (int i = 0; i < 8; ++i) {                           \
      ushort4v cw;                                                            \
      _Pragma("unroll") for (int q = 0; q < 4; ++q) cw[q] = f2bf(Lr[i][q]);   \
      rs[i] += Lr[i][0] + Lr[i][1] + Lr[i][2] + Lr[i][3];                     \
      *(ushort4v*)&sw[(bufofs) + wofs + i * 4 * LDSR] = cw;                   \
    }                                                                         \
  } while (0)

#define LOAD_B(stp)                                                           \
  do {                                                                        \
    const int ktg = kt0 + (stp) * 2;                                          \
    _Pragma("unroll") for (int h = 0; h < 2; ++h)                             \
        _Pragma("unroll") for (int cb = 0; cb < 8; ++cb)                      \
            Bf[h][cb] = *(const ushort8v*)(bp +                               \
                (((size_t)(ktg + h) * 8 + cb) << 9));                         \
  } while (0)

#define MFMA_CLUSTER(bufofs)                                                  \
  do {                                                                        \
    __builtin_amdgcn_s_setprio(1);                                            \
    _Pragma("unroll") for (int h = 0; h < 2; ++h) {                           \
      const int abase = (bufofs) + h * 32 + (l >> 4) * 8;                     \
      short8 aF0 = *(const short8*)&sw[abase + (l & 15) * LDSR];              \
      short8 aF1 = *(const short8*)&sw[abase + (16 + (l & 15)) * LDSR];       \
      _Pragma("unroll") for (int cb = 0; cb < 8; ++cb) {                      \
        acc[0][cb] = __builtin_amdgcn_mfma_f32_16x16x32_bf16(                 \
            aF0, Bf[h][cb], acc[0][cb], 0, 0, 0);                             \
        acc[1][cb] = __builtin_amdgcn_mfma_f32_16x16x32_bf16(                 \
            aF1, Bf[h][cb], acc[1][cb], 0, 0, 0);                             \
      }                                                                       \
    }                                                                         \
    __builtin_amdgcn_s_setprio(0);                                            \
  } while (0)

template <int S>
__global__ __launch_bounds__(256, 2) void gcn_mm(
    const float* __restrict__ adj, const unsigned short* __restrict__ bfrag,
    unsigned short* __restrict__ parts, float* __restrict__ rowpart) {
  constexpr int KW = NN / S;       // K per slot
  constexpr int NS = KW / BK;      // steps per wave (16 at S=8)
  __shared__ __align__(16) unsigned short sA[4][2][32 * LDSR];  // 36.9 KB

  const int t = threadIdx.x;
  const int l = t & 63;
  const int w = t >> 6;
  const int b = blockIdx.x;
  const int s = b & (S - 1);                    // K-slot == XCD (round-robin)
  const int row0 = (b / S) * 128 + w * 32;      // this wave's 32 rows
  const int kbase = s * KW;
  const int kt0 = s * (KW / 32);

  // load geometry: instr i(0..7), lane l -> row = i*4 + (l>>4), k_f32 = (l&15)*4
  const float* ap = adj + (size_t)(row0 + (l >> 4)) * NN + kbase + (l & 15) * 4;
  unsigned short* sw = &sA[w][0][0];
  const int wofs = (l >> 4) * LDSR + (l & 15) * 4;
  const int B1OFS = 32 * LDSR;
  const unsigned short* bp = bfrag + (size_t)l * 8;

  f32x4 LrA[8], LrB[8];            // even-step / odd-step register stages
  ushort8v Bf[2][8];
  f32x4 acc[2][8] = {};
  float rs[8] = {0.f, 0.f, 0.f, 0.f, 0.f, 0.f, 0.f, 0.f};

  // prologue
  PREFETCH(LrA, 0);
  STAGE(LrA, 0);                   // step 0 -> buf0 (cold wait)
  PREFETCH(LrB, 1);                // step 1 in flight

  for (int st = 0; st < NS; st += 2) {
    // ---- even half-step: consume buf0 ----
    LOAD_B(st);                                // L2 loads FIRST
    if (st + 2 < NS) PREFETCH(LrA, st + 2);    // HBM loads AFTER (vmcnt order!)
    __builtin_amdgcn_sched_barrier(0);         // pin issue order
    MFMA_CLUSTER(0);                           // waits vmcnt(8): Bf only
    STAGE(LrB, B1OFS);                         // LrB older than Bf: no wait
    // ---- odd half-step: consume buf1 ----
    LOAD_B(st + 1);
    if (st + 3 < NS) PREFETCH(LrB, st + 3);
    __builtin_amdgcn_sched_barrier(0);
    MFMA_CLUSTER(B1OFS);
    if (st + 2 < NS) STAGE(LrA, 0);            // A(st+2) implicitly arrived
  }

  // ---- rowsum: reduce over 16 k-chunk lanes; lane (l&15)==0 holds the sum ----
  #pragma unroll
  for (int i = 0; i < 8; ++i) {
    rs[i] += __shfl_xor(rs[i], 1);
    rs[i] += __shfl_xor(rs[i], 2);
    rs[i] += __shfl_xor(rs[i], 4);
    rs[i] += __shfl_xor(rs[i], 8);
  }
  if ((l & 15) == 0) {
    #pragma unroll
    for (int i = 0; i < 8; ++i)
      rowpart[(size_t)s * NN + row0 + i * 4 + (l >> 4)] = rs[i];
  }

  // ---- store bf16 partial tile: C/D col = l&15, row = (l>>4)*4 + j ----
  unsigned short* pp = parts + ((size_t)s * NN + row0) * FD;
  #pragma unroll
  for (int rf = 0; rf < 2; ++rf)
    #pragma unroll
    for (int cb = 0; cb < 8; ++cb)
      #pragma unroll
      for (int j = 0; j < 4; ++j) {
        const int r = rf * 16 + ((l >> 4) << 2) + j;
        pp[(size_t)r * FD + cb * 16 + (l & 15)] = f2bf(acc[rf][cb][j]);
      }
}

// -------- Kernel 3: reduce S partials + epilogue ---------------------------
__global__ __launch_bounds__(256) void gcn_fin(
    const unsigned short* __restrict__ parts, const float* __restrict__ rowpart,
    const unsigned short* __restrict__ xk_rm, const float* __restrict__ beta,
    const float* __restrict__ bias, float* __restrict__ out, int S) {
  const int t = threadIdx.x;
  const int r = blockIdx.x * 16 + (t >> 4);
  const int c0 = (t & 15) * 8;

  float rsum = 0.f;
  for (int s = 0; s < S; ++s) rsum += rowpart[(size_t)s * NN + r];
  const float bt = beta[r];
  const float inv = 1.0f / (rsum + bt);

  float a[8] = {0.f, 0.f, 0.f, 0.f, 0.f, 0.f, 0.f, 0.f};
  for (int s = 0; s < S; ++s) {
    ushort8v pv = *(const ushort8v*)&parts[((size_t)s * NN + r) * FD + c0];
    #pragma unroll
    for (int q = 0; q < 8; ++q) a[q] += bf2f(pv[q]);
  }
  ushort8v xv = *(const ushort8v*)&xk_rm[(size_t)r * FD + c0];
  f32x4 o0, o1;
  #pragma unroll
  for (int q = 0; q < 4; ++q) {
    o0[q] = (a[q] + bt * bf2f(xv[q])) * inv + bias[c0 + q];
    o1[q] = (a[4 + q] + bt * bf2f(xv[4 + q])) * inv + bias[c0 + 4 + q];
  }
  *(f32x4*)&out[(size_t)r * FD + c0] = o0;
  *(f32x4*)&out[(size_t)r * FD + c0 + 4] = o1;
}

extern "C" void kernel_launch(void* const* d_in, const int* in_sizes, int n_in,
                              void* d_out, int out_size, void* d_ws, size_t ws_size,
                              hipStream_t stream) {
  const float* x    = (const float*)d_in[0];
  const float* adj  = (const float*)d_in[1];
  const float* kern = (const float*)d_in[2];
  const float* bias = (const float*)d_in[3];
  const float* beta = (const float*)d_in[4];
  float* out = (float*)d_out;

  char* ws = (char*)d_ws;
  unsigned short* bfrag = (unsigned short*)ws;                          // 2 MB
  unsigned short* xk_rm = (unsigned short*)(ws + (size_t)NN * FD * 2);  // 2 MB
  const size_t off_rowpart = (size_t)NN * FD * 4;
  float* rowpart = (float*)(ws + off_rowpart);                          // 256 KB
  const size_t off_parts = off_rowpart + (size_t)8 * NN * 4;
  unsigned short* parts = (unsigned short*)(ws + off_parts);            // 16 MB @ S=8

  int S = 8;
  while (S > 1 && off_parts + (size_t)S * NN * FD * 2 > ws_size) S >>= 1;

  hipLaunchKernelGGL(xk_kernel, dim3(NN / 16), dim3(256), 0, stream,
                     x, kern, bfrag, xk_rm);

  dim3 blk(256);
  switch (S) {
    case 8: hipLaunchKernelGGL(gcn_mm<8>, dim3(64 * 8), blk, 0, stream, adj, bfrag, parts, rowpart); break;
    case 4: hipLaunchKernelGGL(gcn_mm<4>, dim3(64 * 4), blk, 0, stream, adj, bfrag, parts, rowpart); break;
    case 2: hipLaunchKernelGGL(gcn_mm<2>, dim3(64 * 2), blk, 0, stream, adj, bfrag, parts, rowpart); break;
    default: hipLaunchKernelGGL(gcn_mm<1>, dim3(64), blk, 0, stream, adj, bfrag, parts, rowpart); break;
  }

  hipLaunchKernelGGL(gcn_fin, dim3(NN / 16), dim3(256), 0, stream,
                     parts, rowpart, xk_rm, beta, bias, out, S);
}

// Round 7
// 81.136 us; speedup vs baseline: 1.0456x; 1.0456x over previous
//
#include <hip/hip_runtime.h>

#define NN 8192
#define FD 128
#define BKW 128   // K per step (f32 elems); per-row chunk = 512 B contiguous

typedef float f32x4 __attribute__((ext_vector_type(4)));
typedef short short8 __attribute__((ext_vector_type(8)));
typedef unsigned short ushort4v __attribute__((ext_vector_type(4)));
typedef unsigned short ushort8v __attribute__((ext_vector_type(8)));

__device__ __forceinline__ unsigned short f2bf(float f) {
  unsigned int u = __builtin_bit_cast(unsigned int, f);
  u += 0x7fffu + ((u >> 16) & 1u);   // round-to-nearest-even
  return (unsigned short)(u >> 16);
}
__device__ __forceinline__ float bf2f(unsigned short h) {
  unsigned int u = ((unsigned int)h) << 16;
  return __builtin_bit_cast(float, u);
}

// -------- Kernel 1: xk = x@kern (bf16), emitted as MFMA B-fragments + row-major
// bfrag[((kt*8 + cb)*64 + lane)*8 + j] = xk[kt*32 + (lane>>4)*8 + j][cb*16 + (lane&15)]
__global__ __launch_bounds__(256) void xk_kernel(
    const float* __restrict__ x, const float* __restrict__ kern,
    unsigned short* __restrict__ bfrag, unsigned short* __restrict__ xk_rm) {
  __shared__ __align__(16) unsigned short kl[FD * FD];
  __shared__ __align__(16) float xl[16 * FD];
  const int t = threadIdx.x;
  const int row0 = blockIdx.x * 16;

  #pragma unroll
  for (int j = 0; j < 16; ++j) {
    int idx = (j * 256 + t) * 4;
    f32x4 kv = *(const f32x4*)&kern[idx];
    ushort4v kw;
    #pragma unroll
    for (int q = 0; q < 4; ++q) kw[q] = f2bf(kv[q]);
    *(ushort4v*)&kl[idx] = kw;
  }
  #pragma unroll
  for (int j = 0; j < 2; ++j) {
    int idx = (j * 256 + t) * 4;
    *(f32x4*)&xl[idx] = *(const f32x4*)&x[(size_t)row0 * FD + idx];
  }
  __syncthreads();

  const int r0 = (t >> 5) * 2;
  const int c0 = (t & 31) * 4;
  float acc[2][4] = {};
  #pragma unroll 4
  for (int k = 0; k < FD; ++k) {
    ushort4v kq = *(const ushort4v*)&kl[k * FD + c0];
    float kv[4];
    #pragma unroll
    for (int q = 0; q < 4; ++q) kv[q] = bf2f(kq[q]);
    float x0 = xl[r0 * FD + k];
    float x1 = xl[(r0 + 1) * FD + k];
    #pragma unroll
    for (int q = 0; q < 4; ++q) {
      acc[0][q] += x0 * kv[q];
      acc[1][q] += x1 * kv[q];
    }
  }
  #pragma unroll
  for (int i = 0; i < 2; ++i) {
    const int r = row0 + r0 + i;
    const int kt = r >> 5;
    const int lhi = ((r >> 3) & 3) * 16;
    const int j = r & 7;
    ushort4v ow;
    #pragma unroll
    for (int q = 0; q < 4; ++q) {
      const int c = c0 + q;
      unsigned short bv = f2bf(acc[i][q]);
      ow[q] = bv;
      bfrag[(((size_t)kt * 8 + (c >> 4)) * 64 + (lhi + (c & 15))) * 8 + j] = bv;
    }
    *(ushort4v*)&xk_rm[(size_t)r * FD + c0] = ow;
  }
}

// -------- Kernel 2: split-K MFMA, 512B-contiguous A bursts, XOR-swz LDS -----
#define PREF_A(stp)                                                           \
  do {                                                                        \
    _Pragma("unroll") for (int i = 0; i < 16; ++i)                            \
        Lr[i] = *(const f32x4*)(ap + (size_t)2 * i * NN + (stp) * BKW);       \
  } while (0)

#define STAGE_A(bufofs)                                                       \
  do {                                                                        \
    _Pragma("unroll") for (int i = 0; i < 16; ++i) {                          \
      ushort4v cw;                                                            \
      _Pragma("unroll") for (int q = 0; q < 4; ++q) cw[q] = f2bf(Lr[i][q]);   \
      rs[i] += Lr[i][0] + Lr[i][1] + Lr[i][2] + Lr[i][3];                     \
      const int row_l = 2 * i + rl2;                                          \
      *(ushort4v*)&sw0[(bufofs) + row_l * 128 +                               \
                       (kc4 ^ ((row_l & 7) << 3))] = cw;                      \
    }                                                                         \
  } while (0)

#define LOAD_B2(ktg)                                                          \
  do {                                                                        \
    _Pragma("unroll") for (int h = 0; h < 2; ++h)                             \
        _Pragma("unroll") for (int cb = 0; cb < 8; ++cb)                      \
            Bf[h][cb] = *(const ushort8v*)(bp +                               \
                (((size_t)((ktg) + h) * 8 + cb) << 9));                       \
  } while (0)

#define CMP2(bufofs, ktl)                                                     \
  do {                                                                        \
    short8 aF0[2], aF1[2];                                                    \
    _Pragma("unroll") for (int h = 0; h < 2; ++h) {                           \
      const int colu = ((ktl) + h) * 32 + (l >> 4) * 8;                       \
      const int ra = l & 15;                                                  \
      const int rb2 = 16 + ra;                                                \
      aF0[h] = *(const short8*)&sw0[(bufofs) + ra * 128 +                     \
                                    (colu ^ ((ra & 7) << 3))];                \
      aF1[h] = *(const short8*)&sw0[(bufofs) + rb2 * 128 +                    \
                                    (colu ^ ((rb2 & 7) << 3))];               \
    }                                                                         \
    __builtin_amdgcn_s_setprio(1);                                            \
    _Pragma("unroll") for (int h = 0; h < 2; ++h)                             \
        _Pragma("unroll") for (int cb = 0; cb < 8; ++cb) {                    \
          acc[0][cb] = __builtin_amdgcn_mfma_f32_16x16x32_bf16(               \
              aF0[h], Bf[h][cb], acc[0][cb], 0, 0, 0);                        \
          acc[1][cb] = __builtin_amdgcn_mfma_f32_16x16x32_bf16(               \
              aF1[h], Bf[h][cb], acc[1][cb], 0, 0, 0);                        \
        }                                                                     \
    __builtin_amdgcn_s_setprio(0);                                            \
  } while (0)

template <int S>
__global__ __launch_bounds__(256, 2) void gcn_mm(
    const float* __restrict__ adj, const unsigned short* __restrict__ bfrag,
    unsigned short* __restrict__ parts, float* __restrict__ rowpart) {
  constexpr int KW = NN / S;       // K per slot
  constexpr int NS = KW / BKW;     // steps (8 at S=8)
  constexpr int BUFO = 32 * 128;   // ushorts per buffer
  __shared__ unsigned short sA[4][2][BUFO];   // 64 KB exact

  const int t = threadIdx.x;
  const int l = t & 63;
  const int w = t >> 6;
  const int b = blockIdx.x;
  const int s = b & (S - 1);                  // K-slot == XCD (round-robin)
  const int row0 = (b / S) * 128 + w * 32;    // wave's 32 rows
  const int kbase = s * KW;
  const int kt0 = s * (KW / 32);

  // A geometry: instr i -> rows 2i, 2i+1; each 32-lane half reads 512 B contig
  const int rl2 = l >> 5;                     // 0/1: which row of the pair
  const int kc4 = (l & 31) * 4;               // k-offset in elems (f32/ushort)
  const float* ap = adj + (size_t)(row0 + rl2) * NN + kbase + kc4;

  unsigned short* sw0 = &sA[w][0][0];
  const unsigned short* bp = bfrag + (size_t)l * 8;

  f32x4 Lr[16];
  ushort8v Bf[2][8];
  f32x4 acc[2][8] = {};
  float rs[16] = {};

  // prologue: stage step 0
  PREF_A(0);
  STAGE_A(0);

  for (int st = 0; st < NS; ++st) {
    const int bo = (st & 1) * BUFO;
    const int nbo = bo ^ BUFO;
    const int ktg = kt0 + st * 4;
    LOAD_B2(ktg);                            // B first (oldest in queue)
    __builtin_amdgcn_sched_barrier(0);
    if (st + 1 < NS) PREF_A(st + 1);         // A after B: CMP waits vmcnt(16)
    __builtin_amdgcn_sched_barrier(0);
    CMP2(bo, 0);                             // pure-B wait, A stays in flight
    LOAD_B2(ktg + 2);                        // reuse Bf regs
    __builtin_amdgcn_sched_barrier(0);
    CMP2(bo, 2);                             // drains A (landed by now)
    if (st + 1 < NS) STAGE_A(nbo);
  }

  // ---- rowsum: reduce within each 32-lane half (rows 2i / 2i+1) ----
  #pragma unroll
  for (int i = 0; i < 16; ++i) {
    rs[i] += __shfl_xor(rs[i], 1);
    rs[i] += __shfl_xor(rs[i], 2);
    rs[i] += __shfl_xor(rs[i], 4);
    rs[i] += __shfl_xor(rs[i], 8);
    rs[i] += __shfl_xor(rs[i], 16);
  }
  if ((l & 31) == 0) {
    #pragma unroll
    for (int i = 0; i < 16; ++i)
      rowpart[(size_t)s * NN + row0 + 2 * i + rl2] = rs[i];
  }

  // ---- store bf16 partial tile: C/D col = l&15, row = (l>>4)*4 + j ----
  unsigned short* pp = parts + ((size_t)s * NN + row0) * FD;
  #pragma unroll
  for (int rf = 0; rf < 2; ++rf)
    #pragma unroll
    for (int cb = 0; cb < 8; ++cb)
      #pragma unroll
      for (int j = 0; j < 4; ++j) {
        const int r = rf * 16 + ((l >> 4) << 2) + j;
        pp[(size_t)r * FD + cb * 16 + (l & 15)] = f2bf(acc[rf][cb][j]);
      }
}

// -------- Kernel 3: reduce S partials + epilogue ---------------------------
__global__ __launch_bounds__(256) void gcn_fin(
    const unsigned short* __restrict__ parts, const float* __restrict__ rowpart,
    const unsigned short* __restrict__ xk_rm, const float* __restrict__ beta,
    const float* __restrict__ bias, float* __restrict__ out, int S) {
  const int t = threadIdx.x;
  const int r = blockIdx.x * 16 + (t >> 4);
  const int c0 = (t & 15) * 8;

  float rsum = 0.f;
  for (int s = 0; s < S; ++s) rsum += rowpart[(size_t)s * NN + r];
  const float bt = beta[r];
  const float inv = 1.0f / (rsum + bt);

  float a[8] = {0.f, 0.f, 0.f, 0.f, 0.f, 0.f, 0.f, 0.f};
  for (int s = 0; s < S; ++s) {
    ushort8v pv = *(const ushort8v*)&parts[((size_t)s * NN + r) * FD + c0];
    #pragma unroll
    for (int q = 0; q < 8; ++q) a[q] += bf2f(pv[q]);
  }
  ushort8v xv = *(const ushort8v*)&xk_rm[(size_t)r * FD + c0];
  f32x4 o0, o1;
  #pragma unroll
  for (int q = 0; q < 4; ++q) {
    o0[q] = (a[q] + bt * bf2f(xv[q])) * inv + bias[c0 + q];
    o1[q] = (a[4 + q] + bt * bf2f(xv[4 + q])) * inv + bias[c0 + 4 + q];
  }
  *(f32x4*)&out[(size_t)r * FD + c0] = o0;
  *(f32x4*)&out[(size_t)r * FD + c0 + 4] = o1;
}

extern "C" void kernel_launch(void* const* d_in, const int* in_sizes, int n_in,
                              void* d_out, int out_size, void* d_ws, size_t ws_size,
                              hipStream_t stream) {
  const float* x    = (const float*)d_in[0];
  const float* adj  = (const float*)d_in[1];
  const float* kern = (const float*)d_in[2];
  const float* bias = (const float*)d_in[3];
  const float* beta = (const float*)d_in[4];
  float* out = (float*)d_out;

  char* ws = (char*)d_ws;
  unsigned short* bfrag = (unsigned short*)ws;                          // 2 MB
  unsigned short* xk_rm = (unsigned short*)(ws + (size_t)NN * FD * 2);  // 2 MB
  const size_t off_rowpart = (size_t)NN * FD * 4;
  float* rowpart = (float*)(ws + off_rowpart);                          // 256 KB
  const size_t off_parts = off_rowpart + (size_t)8 * NN * 4;
  unsigned short* parts = (unsigned short*)(ws + off_parts);            // 16 MB @ S=8

  int S = 8;
  while (S > 1 && off_parts + (size_t)S * NN * FD * 2 > ws_size) S >>= 1;

  hipLaunchKernelGGL(xk_kernel, dim3(NN / 16), dim3(256), 0, stream,
                     x, kern, bfrag, xk_rm);

  dim3 blk(256);
  switch (S) {
    case 8: hipLaunchKernelGGL(gcn_mm<8>, dim3(64 * 8), blk, 0, stream, adj, bfrag, parts, rowpart); break;
    case 4: hipLaunchKernelGGL(gcn_mm<4>, dim3(64 * 4), blk, 0, stream, adj, bfrag, parts, rowpart); break;
    case 2: hipLaunchKernelGGL(gcn_mm<2>, dim3(64 * 2), blk, 0, stream, adj, bfrag, parts, rowpart); break;
    default: hipLaunchKernelGGL(gcn_mm<1>, dim3(64), blk, 0, stream, adj, bfrag, parts, rowpart); break;
  }

  hipLaunchKernelGGL(gcn_fin, dim3(NN / 16), dim3(256), 0, stream,
                     parts, rowpart, xk_rm, beta, bias, out, S);
}

// Round 8
// 80.154 us; speedup vs baseline: 1.0584x; 1.0122x over previous
//
#include <hip/hip_runtime.h>

#define NN 8192
#define FD 128
#define BK 128    // K per step (f32 elems)

typedef float f32x4 __attribute__((ext_vector_type(4)));
typedef short short8 __attribute__((ext_vector_type(8)));
typedef unsigned short ushort4v __attribute__((ext_vector_type(4)));
typedef unsigned short ushort8v __attribute__((ext_vector_type(8)));

__device__ __forceinline__ unsigned short f2bf(float f) {
  unsigned int u = __builtin_bit_cast(unsigned int, f);
  u += 0x7fffu + ((u >> 16) & 1u);   // round-to-nearest-even
  return (unsigned short)(u >> 16);
}
__device__ __forceinline__ float bf2f(unsigned short h) {
  unsigned int u = ((unsigned int)h) << 16;
  return __builtin_bit_cast(float, u);
}

// -------- Kernel 1: xk = x@kern (bf16), emitted as MFMA B-fragments + row-major
// bfrag[((kt*8 + cb)*64 + lane)*8 + j] = xk[kt*32 + (lane>>4)*8 + j][cb*16 + (lane&15)]
__global__ __launch_bounds__(256) void xk_kernel(
    const float* __restrict__ x, const float* __restrict__ kern,
    unsigned short* __restrict__ bfrag, unsigned short* __restrict__ xk_rm) {
  __shared__ __align__(16) unsigned short kl[FD * FD];
  __shared__ __align__(16) float xl[16 * FD];
  const int t = threadIdx.x;
  const int row0 = blockIdx.x * 16;

  #pragma unroll
  for (int j = 0; j < 16; ++j) {
    int idx = (j * 256 + t) * 4;
    f32x4 kv = *(const f32x4*)&kern[idx];
    ushort4v kw;
    #pragma unroll
    for (int q = 0; q < 4; ++q) kw[q] = f2bf(kv[q]);
    *(ushort4v*)&kl[idx] = kw;
  }
  #pragma unroll
  for (int j = 0; j < 2; ++j) {
    int idx = (j * 256 + t) * 4;
    *(f32x4*)&xl[idx] = *(const f32x4*)&x[(size_t)row0 * FD + idx];
  }
  __syncthreads();

  const int r0 = (t >> 5) * 2;
  const int c0 = (t & 31) * 4;
  float acc[2][4] = {};
  #pragma unroll 4
  for (int k = 0; k < FD; ++k) {
    ushort4v kq = *(const ushort4v*)&kl[k * FD + c0];
    float kv[4];
    #pragma unroll
    for (int q = 0; q < 4; ++q) kv[q] = bf2f(kq[q]);
    float x0 = xl[r0 * FD + k];
    float x1 = xl[(r0 + 1) * FD + k];
    #pragma unroll
    for (int q = 0; q < 4; ++q) {
      acc[0][q] += x0 * kv[q];
      acc[1][q] += x1 * kv[q];
    }
  }
  #pragma unroll
  for (int i = 0; i < 2; ++i) {
    const int r = row0 + r0 + i;
    const int kt = r >> 5;
    const int lhi = ((r >> 3) & 3) * 16;
    const int j = r & 7;
    ushort4v ow;
    #pragma unroll
    for (int q = 0; q < 4; ++q) {
      const int c = c0 + q;
      unsigned short bv = f2bf(acc[i][q]);
      ow[q] = bv;
      bfrag[(((size_t)kt * 8 + (c >> 4)) * 64 + (lhi + (c & 15))) * 8 + j] = bv;
    }
    *(ushort4v*)&xk_rm[(size_t)r * FD + c0] = ow;
  }
}

// -------- Kernel 2: split-K MFMA, 16 waves/CU, block-cooperative A stage ----
// Block = 32 rows x 128 cols x (NN/S) K-slice; wave w owns cols [w*32,w*32+32).
#define PREF(Lr, stp)                                                         \
  do {                                                                        \
    _Pragma("unroll") for (int i = 0; i < 4; ++i)                             \
        Lr[i] = *(const f32x4*)(ap + (size_t)(i * 8) * NN + (stp) * BK);      \
  } while (0)

#define STAGE(Lr, buf)                                                        \
  do {                                                                        \
    _Pragma("unroll") for (int i = 0; i < 4; ++i) {                           \
      ushort4v cw;                                                            \
      _Pragma("unroll") for (int q = 0; q < 4; ++q) cw[q] = f2bf(Lr[i][q]);   \
      rs[i] += Lr[i][0] + Lr[i][1] + Lr[i][2] + Lr[i][3];                     \
      const int row_l = i * 8 + srow;                                         \
      *(ushort4v*)&sA[buf][row_l * 128 +                                      \
                           (scol ^ ((row_l & 7) << 3))] = cw;                 \
    }                                                                         \
  } while (0)

#define LOAD_B(stp)                                                           \
  do {                                                                        \
    const int ktg = kt0 + (stp) * 4;                                          \
    _Pragma("unroll") for (int kk = 0; kk < 4; ++kk)                          \
        _Pragma("unroll") for (int ci = 0; ci < 2; ++ci)                      \
            Bf[kk * 2 + ci] = *(const ushort8v*)(bp +                         \
                (((size_t)(ktg + kk) * 8 + (w * 2 + ci)) << 9));              \
  } while (0)

#define MFMA_STEP(buf)                                                        \
  do {                                                                        \
    __builtin_amdgcn_s_setprio(1);                                            \
    _Pragma("unroll") for (int kk = 0; kk < 4; ++kk) {                        \
      short8 aF[2];                                                           \
      _Pragma("unroll") for (int mf = 0; mf < 2; ++mf) {                      \
        const int r = mf * 16 + (l & 15);                                     \
        const int colu = kk * 32 + (l >> 4) * 8;                              \
        aF[mf] = *(const short8*)&sA[buf][r * 128 +                           \
                                          (colu ^ ((r & 7) << 3))];           \
      }                                                                       \
      _Pragma("unroll") for (int mf = 0; mf < 2; ++mf)                        \
          _Pragma("unroll") for (int ci = 0; ci < 2; ++ci)                    \
              acc[mf][ci] = __builtin_amdgcn_mfma_f32_16x16x32_bf16(          \
                  aF[mf], Bf[kk * 2 + ci], acc[mf][ci], 0, 0, 0);             \
    }                                                                         \
    __builtin_amdgcn_s_setprio(0);                                            \
  } while (0)

#define LDS_BARRIER()                                                         \
  do {                                                                        \
    asm volatile("s_waitcnt lgkmcnt(0)" ::: "memory");                        \
    __builtin_amdgcn_sched_barrier(0);                                        \
    __builtin_amdgcn_s_barrier();                                             \
  } while (0)

template <int S>
__global__ __launch_bounds__(256, 4) void gcn_mm(
    const float* __restrict__ adj, const unsigned short* __restrict__ bfrag,
    unsigned short* __restrict__ parts, float* __restrict__ rowpart) {
  constexpr int KW = NN / S;       // K per slot
  constexpr int NS = KW / BK;      // steps (8 at S=8), always even
  __shared__ unsigned short sA[2][32 * 128];   // 16 KB

  const int t = threadIdx.x;
  const int l = t & 63;
  const int w = t >> 6;
  const int b = blockIdx.x;
  const int s = b & (S - 1);                  // K-slot == XCD (round-robin)
  const int row0 = (b / S) * 32;              // block's 32 rows
  const int kbase = s * KW;
  const int kt0 = s * (KW / 32);

  // A stage geometry: instr i, thread t -> row = i*8 + (t>>5), 512B/row chunks
  const int srow = t >> 5;                    // 0..7
  const int scol = (t & 31) * 4;              // f32 (and bf16) col within step
  const float* ap = adj + (size_t)(row0 + srow) * NN + kbase + scol;
  const unsigned short* bp = bfrag + (size_t)l * 8;

  f32x4 LrA[4], LrB[4];            // depth-2 A register stages
  ushort8v Bf[8];
  f32x4 acc[2][2] = {};
  float rs[4] = {};

  // prologue
  PREF(LrA, 0);
  STAGE(LrA, 0);                   // cold wait on step 0
  PREF(LrB, 1);                    // step 1 in flight across step 0's MFMA
  LDS_BARRIER();

  for (int st = 0; st < NS; st += 2) {
    // even: consume buf0
    LOAD_B(st);                                // B younger than A(st+1) queue-wise
    if (st + 2 < NS) PREF(LrA, st + 2);
    __builtin_amdgcn_sched_barrier(0);
    MFMA_STEP(0);                              // waits B only; A(st+2) survives
    STAGE(LrB, 1);                             // A(st+1): issued a full step ago
    LDS_BARRIER();
    // odd: consume buf1
    LOAD_B(st + 1);
    if (st + 3 < NS) PREF(LrB, st + 3);
    __builtin_amdgcn_sched_barrier(0);
    MFMA_STEP(1);
    if (st + 2 < NS) STAGE(LrA, 0);
    LDS_BARRIER();
  }

  // ---- rowsum: reduce over the 32 k-lanes sharing each row ----
  #pragma unroll
  for (int i = 0; i < 4; ++i) {
    rs[i] += __shfl_xor(rs[i], 1);
    rs[i] += __shfl_xor(rs[i], 2);
    rs[i] += __shfl_xor(rs[i], 4);
    rs[i] += __shfl_xor(rs[i], 8);
    rs[i] += __shfl_xor(rs[i], 16);
  }
  if ((l & 31) == 0) {
    #pragma unroll
    for (int i = 0; i < 4; ++i)
      rowpart[(size_t)s * NN + row0 + i * 8 + srow] = rs[i];
  }

  // ---- store bf16 partial tile: C/D col = l&15, row = (l>>4)*4 + j ----
  unsigned short* pp = parts + ((size_t)s * NN + row0) * FD + w * 32;
  #pragma unroll
  for (int mf = 0; mf < 2; ++mf)
    #pragma unroll
    for (int ci = 0; ci < 2; ++ci)
      #pragma unroll
      for (int j = 0; j < 4; ++j) {
        const int r = mf * 16 + ((l >> 4) << 2) + j;
        pp[(size_t)r * FD + ci * 16 + (l & 15)] = f2bf(acc[mf][ci][j]);
      }
}

// -------- Kernel 3: reduce S partials + epilogue ---------------------------
__global__ __launch_bounds__(256) void gcn_fin(
    const unsigned short* __restrict__ parts, const float* __restrict__ rowpart,
    const unsigned short* __restrict__ xk_rm, const float* __restrict__ beta,
    const float* __restrict__ bias, float* __restrict__ out, int S) {
  const int t = threadIdx.x;
  const int r = blockIdx.x * 16 + (t >> 4);
  const int c0 = (t & 15) * 8;

  float rsum = 0.f;
  for (int s = 0; s < S; ++s) rsum += rowpart[(size_t)s * NN + r];
  const float bt = beta[r];
  const float inv = 1.0f / (rsum + bt);

  float a[8] = {0.f, 0.f, 0.f, 0.f, 0.f, 0.f, 0.f, 0.f};
  for (int s = 0; s < S; ++s) {
    ushort8v pv = *(const ushort8v*)&parts[((size_t)s * NN + r) * FD + c0];
    #pragma unroll
    for (int q = 0; q < 8; ++q) a[q] += bf2f(pv[q]);
  }
  ushort8v xv = *(const ushort8v*)&xk_rm[(size_t)r * FD + c0];
  f32x4 o0, o1;
  #pragma unroll
  for (int q = 0; q < 4; ++q) {
    o0[q] = (a[q] + bt * bf2f(xv[q])) * inv + bias[c0 + q];
    o1[q] = (a[4 + q] + bt * bf2f(xv[4 + q])) * inv + bias[c0 + 4 + q];
  }
  *(f32x4*)&out[(size_t)r * FD + c0] = o0;
  *(f32x4*)&out[(size_t)r * FD + c0 + 4] = o1;
}

extern "C" void kernel_launch(void* const* d_in, const int* in_sizes, int n_in,
                              void* d_out, int out_size, void* d_ws, size_t ws_size,
                              hipStream_t stream) {
  const float* x    = (const float*)d_in[0];
  const float* adj  = (const float*)d_in[1];
  const float* kern = (const float*)d_in[2];
  const float* bias = (const float*)d_in[3];
  const float* beta = (const float*)d_in[4];
  float* out = (float*)d_out;

  char* ws = (char*)d_ws;
  unsigned short* bfrag = (unsigned short*)ws;                          // 2 MB
  unsigned short* xk_rm = (unsigned short*)(ws + (size_t)NN * FD * 2);  // 2 MB
  const size_t off_rowpart = (size_t)NN * FD * 4;
  float* rowpart = (float*)(ws + off_rowpart);                          // 256 KB
  const size_t off_parts = off_rowpart + (size_t)8 * NN * 4;
  unsigned short* parts = (unsigned short*)(ws + off_parts);            // 16 MB @ S=8

  int S = 8;
  while (S > 1 && off_parts + (size_t)S * NN * FD * 2 > ws_size) S >>= 1;

  hipLaunchKernelGGL(xk_kernel, dim3(NN / 16), dim3(256), 0, stream,
                     x, kern, bfrag, xk_rm);

  dim3 blk(256);
  switch (S) {
    case 8: hipLaunchKernelGGL(gcn_mm<8>, dim3(256 * 8), blk, 0, stream, adj, bfrag, parts, rowpart); break;
    case 4: hipLaunchKernelGGL(gcn_mm<4>, dim3(256 * 4), blk, 0, stream, adj, bfrag, parts, rowpart); break;
    case 2: hipLaunchKernelGGL(gcn_mm<2>, dim3(256 * 2), blk, 0, stream, adj, bfrag, parts, rowpart); break;
    default: hipLaunchKernelGGL(gcn_mm<1>, dim3(256), blk, 0, stream, adj, bfrag, parts, rowpart); break;
  }

  hipLaunchKernelGGL(gcn_fin, dim3(NN / 16), dim3(256), 0, stream,
                     parts, rowpart, xk_rm, beta, bias, out, S);
}